// Round 17
// baseline (149.913 us; speedup 1.0000x reference)
//
#include <hip/hip_runtime.h>
#include <math.h>

#define B_SZ 512
#define LG 48
#define T_LEN 128
#define DIM 300
#define NA 2048
#define NC 2048
#define NH 4
#define DK 75
#define KTOP 96
#define ACAP 16
#define TM 64
#define TN 64
#define NGK 25     // k-groups per split chunk (3 x 100)
#define WSS 108    // ws row stride: 12*tx mod 32 -> 8 windows x 2 lanes = free
#define QKS 608    // padded QK row: 4 heads x 76 (q) + 4 heads x 76 (k)
#define GTM 32
#define GTN 64
#define GKC 60
#define FCAP2 9    // staged rows: nf <= 8 by construction, +1 bias row
#define SSTR 612   // staged row stride (612 mod 32 = 4 -> spread banks)

// ---------------------------------------------------------------------------
// K0: register aspect slots (atomicMax vs -1 init) + per-sentence aspect lists
// ---------------------------------------------------------------------------
__global__ __launch_bounds__(256) void build_kernel(
    const int* __restrict__ mapAA, const int* __restrict__ mapAAi,
    int* __restrict__ slot_src, int* __restrict__ acnt, int* __restrict__ alist) {
  int n = blockIdx.x * 256 + threadIdx.x;
  if (n >= NA) return;
  int b = mapAA[n];
  atomicMax(&slot_src[b * LG + mapAAi[n]], n);
  int pos = atomicAdd(&acnt[b], 1);
  if (pos < ACAP) alist[b * ACAP + pos] = n;
}

// ---------------------------------------------------------------------------
// K1: grouped aspect embedding (unchanged; passed rounds 2-16)
// ---------------------------------------------------------------------------
__global__ __launch_bounds__(256) void aspect_kernel(
    const float* __restrict__ embed, const float* __restrict__ mask,
    const int* __restrict__ acnt, const int* __restrict__ alist,
    float* __restrict__ X) {
  int b = blockIdx.x;
  int na = acnt[b]; if (na > ACAP) na = ACAP;
  if (na == 0) return;
  __shared__ float mLds[ACAP][T_LEN];
  __shared__ float4 eLds[32][DK];
  int tid = threadIdx.x;
  for (int i = tid; i < na * T_LEN; i += 256) {
    int k = i / T_LEN, t = i - k * T_LEN;
    mLds[k][t] = mask[(size_t)alist[b * ACAP + k] * T_LEN + t];
  }
  int nw = na * DK;
  int i0 = tid, i1 = tid + 256;
  int k0 = i0 / DK, d0 = i0 - k0 * DK;
  int k1 = i1 / DK, d1 = i1 - k1 * DK;
  float4 a0 = {0, 0, 0, 0}, a1 = {0, 0, 0, 0};
  const float4* e4 = (const float4*)(embed + (size_t)b * T_LEN * DIM);
  for (int t0 = 0; t0 < T_LEN; t0 += 32) {
    __syncthreads();
    for (int i = tid; i < 32 * DK; i += 256) {
      int t = i / DK, d = i - t * DK;
      eLds[t][d] = e4[(size_t)(t0 + t) * DK + d];
    }
    __syncthreads();
#pragma unroll
    for (int t = 0; t < 32; ++t) {
      if (i0 < nw) {
        float m = mLds[k0][t0 + t]; float4 ev = eLds[t][d0];
        a0.x += m * ev.x; a0.y += m * ev.y; a0.z += m * ev.z; a0.w += m * ev.w;
      }
      if (i1 < nw) {
        float m = mLds[k1][t0 + t]; float4 ev = eLds[t][d1];
        a1.x += m * ev.x; a1.y += m * ev.y; a1.z += m * ev.z; a1.w += m * ev.w;
      }
    }
  }
  if (i0 < nw) ((float4*)(X + (size_t)alist[b * ACAP + k0] * DIM))[d0] = a0;
  if (i1 < nw) ((float4*)(X + (size_t)alist[b * ACAP + k1] * DIM))[d1] = a1;
}

// ---------------------------------------------------------------------------
// K2: clause rows -> X[NA+n]; slot registration (unchanged)
// ---------------------------------------------------------------------------
__global__ __launch_bounds__(128) void clause_kernel(
    const float* __restrict__ clause, const int* __restrict__ mapAS,
    const int* __restrict__ mapASi, float* __restrict__ X,
    int* __restrict__ slot_src) {
  int n = blockIdx.x, t = threadIdx.x;
  const float4* src = (const float4*)(clause + (size_t)n * DIM);
  float4* dst = (float4*)(X + (size_t)(NA + n) * DIM);
  if (t < DIM / 4) dst[t] = src[t];
  if (t == 96) atomicMax(&slot_src[mapAS[n] * LG + mapASi[n]], NA + n);
}

// ---------------------------------------------------------------------------
// K3: QK GEMM v7 — SPLIT-K x3. Grid (64,10,3) = 1920 blocks (7.5/CU), LDS
// 27.6KB -> 5 blocks/CU capacity (was 4 at split-2). z chunk k in
// [100z, 100z+100). Bias-free partials, padded-608 layout; combine
// ((P0+P1)+P2)+bias fused into attn2 staging. Within-partial FMA chain
// strictly k-ascending groups of 4 (unchanged expression).
// ---------------------------------------------------------------------------
__global__ __launch_bounds__(256) void qk_kernel(
    const float* __restrict__ X, const float* __restrict__ Wq,
    const float* __restrict__ Wk, float* __restrict__ QKP) {
  __shared__ __align__(16) float ws[TN][WSS];
  int z = blockIdx.z;
  int kbase = z * 100;
  int m0 = blockIdx.x * TM, n0 = blockIdx.y * TN;
  int tid = threadIdx.x;
  int ty = tid >> 4;
  int tx = tid & 15;
  float acc[4][4];
#pragma unroll
  for (int a = 0; a < 4; ++a)
#pragma unroll
    for (int c = 0; c < 4; ++c) acc[a][c] = 0.f;

  for (int i = tid; i < TN * NGK; i += 256) {
    int c = i / NGK, g = i - c * NGK;
    int col = n0 + c;
    float4 v = {0.f, 0.f, 0.f, 0.f};
    if (col < 2 * DIM) {
      const float* w = (col < DIM) ? (Wq + (size_t)col * DIM)
                                   : (Wk + (size_t)(col - DIM) * DIM);
      v = *(const float4*)&w[kbase + g * 4];
    }
    *(float4*)&ws[c][g * 4] = v;
  }
  __syncthreads();

  const float* xrow[4];
#pragma unroll
  for (int a = 0; a < 4; ++a)
    xrow[a] = X + (size_t)(m0 + ty * 4 + a) * DIM + kbase;

#pragma unroll 5
  for (int kg = 0; kg < NGK; ++kg) {
    float4 xv[4], wv[4];
#pragma unroll
    for (int a = 0; a < 4; ++a) xv[a] = *(const float4*)&xrow[a][kg * 4];
#pragma unroll
    for (int c = 0; c < 4; ++c) wv[c] = *(const float4*)&ws[tx + 16 * c][kg * 4];
#pragma unroll
    for (int a = 0; a < 4; ++a)
#pragma unroll
      for (int c = 0; c < 4; ++c)
        acc[a][c] += wv[c].x * xv[a].x + wv[c].y * xv[a].y +
                     wv[c].z * xv[a].z + wv[c].w * xv[a].w;
  }

  float* out = QKP + (size_t)z * (NA + NC) * QKS;
#pragma unroll
  for (int cc = 0; cc < 4; ++cc) {
    int col = n0 + tx + 16 * cc;
    if (col < 2 * DIM) {
      int off;
      if (col < DIM) off = col + col / DK;
      else { int c2 = col - DIM; off = 304 + c2 + c2 / DK; }
#pragma unroll
      for (int a = 0; a < 4; ++a)
        out[(size_t)(m0 + ty * 4 + a) * QKS + off] = acc[a][cc];
    }
  }
}

// ---------------------------------------------------------------------------
// K4: FUSED attention v3c — round-14/16 code with de-barriered staging:
// phase A (bias row) and phase B (filled rows) are now independent — B reads
// bias from GLOBAL (not staged[nf]) and zeroes pad slots inline (pads are
// provably the .w of groups with g%19==18) -> 2 barriers removed. Combine
// is ((P0+P1)+P2)+bias for split-3. Score/top-k/epilogue verbatim.
// ---------------------------------------------------------------------------
__global__ __launch_bounds__(512) void attn2_kernel(
    const float* __restrict__ QKP, const float* __restrict__ X,
    const float* __restrict__ bq, const float* __restrict__ bk,
    const int* __restrict__ slot_src, const int* __restrict__ aa_len,
    float* __restrict__ xout, float* __restrict__ dng, int* __restrict__ mdg) {
  int b = blockIdx.x, tid = threadIdx.x;
  __shared__ __align__(16) float staged[FCAP2][SSTR];
  __shared__ float buf4[NH][LG][LG + 1];
  __shared__ float coef[4][LG], denomc[4];
  __shared__ int srcs[LG], nlist[LG], flist[LG], qrow[LG];
  __shared__ float kthL;
  __shared__ int sh_nneed, sh_nf;

  int length = aa_len[b];
  if (length > LG) length = LG;
  if (tid < LG) srcs[tid] = slot_src[b * LG + tid];
  __syncthreads();

  if (tid < 64) {
    bool isneed = (tid < LG) && (srcs[tid] >= NA);
    unsigned long long nm = __ballot(isneed);
    if (isneed) nlist[__popcll(nm & ((1ull << tid) - 1ull))] = tid;
    bool isf = (tid < LG) && (srcs[tid] >= 0);
    unsigned long long fm = __ballot(isf);
    int nf = __popcll(fm);
    if (nf > FCAP2 - 1) nf = FCAP2 - 1;
    if (isf) {
      int c = __popcll(fm & ((1ull << tid) - 1ull));
      if (c < FCAP2 - 1) flist[c] = tid;
    }
    if (tid < LG) {
      int c = __popcll(fm & ((1ull << tid) - 1ull));
      qrow[tid] = (isf && c < FCAP2 - 1) ? c : nf;   // nf = bias row
    }
    if (tid == 0) { sh_nneed = __popcll(nm); sh_nf = nf; }
  }
  __syncthreads();
  int nneed = sh_nneed, nf = sh_nf;

  if (length <= 1) {
    if (tid < nneed) mdg[srcs[nlist[tid]] - NA] = 0;
    return;
  }

  // phase A: bias row (pads d>=DK already written as 0)
  for (int j = tid; j < 608; j += 512) {
    int half = (j >= 304) ? 1 : 0;
    int jj = j - half * 304;
    int h = jj / 76, d = jj - h * 76;
    float v = 0.f;
    if (d < DK) v = half ? bk[h * DK + d] : bq[h * DK + d];
    staged[nf][j] = v;
  }
  // phase B: filled rows = ((P0+P1)+P2) + bias, bias from global, pads
  // zeroed inline (.w of g%19==18). Independent of phase A -> no barrier.
  {
    const float* P0 = QKP;
    const float* P1 = QKP + (size_t)(NA + NC) * QKS;
    const float* P2 = QKP + (size_t)2 * (NA + NC) * QKS;
    for (int i = tid; i < nf * 152; i += 512) {
      int m = i / 152, g = i - m * 152;
      size_t base = (size_t)srcs[flist[m]] * QKS + g * 4;
      float4 a = *(const float4*)&P0[base];
      float4 c1 = *(const float4*)&P1[base];
      float4 c2 = *(const float4*)&P2[base];
      float4 v;
      int j0g = g * 4;
      int half = (j0g >= 304) ? 1 : 0;
      int jj = j0g - half * 304;
      int h = jj / 76, d = jj - h * 76;   // d..d+3 within the same 76-block
      const float* bias = half ? bk : bq;
      v.x = ((a.x + c1.x) + c2.x) + ((d + 0 < DK) ? bias[h * DK + d + 0] : 0.f);
      v.y = ((a.y + c1.y) + c2.y) + ((d + 1 < DK) ? bias[h * DK + d + 1] : 0.f);
      v.z = ((a.z + c1.z) + c2.z) + ((d + 2 < DK) ? bias[h * DK + d + 2] : 0.f);
      v.w = ((a.w + c1.w) + c2.w) + ((d + 3 < DK) ? bias[h * DK + d + 3] : 0.f);
      if (g % 19 == 18) v.w = 0.f;   // pad slot (partials hold garbage there)
      *(float4*)&staged[m][g * 4] = v;
    }
  }
  __syncthreads();

  const float sdk = sqrtf((float)DK);
  int h = tid >> 7;            // head index 0..3 (128 threads each)
  int t = tid & 127;
  int ti = t >> 3, tj = t & 7;
  int i0 = ti * 3, j0 = tj * 6;

  int qr[3], kr[6];
#pragma unroll
  for (int a = 0; a < 3; ++a) qr[a] = qrow[i0 + a];
#pragma unroll
  for (int c = 0; c < 6; ++c) kr[c] = qrow[j0 + c];

  if (i0 < length) {
    float acc[3][6];
#pragma unroll
    for (int a = 0; a < 3; ++a)
#pragma unroll
      for (int c = 0; c < 6; ++c) acc[a][c] = 0.f;
    for (int d4 = 0; d4 < 19; ++d4) {
      float4 qv[3], kv[6];
#pragma unroll
      for (int a = 0; a < 3; ++a)
        qv[a] = *(const float4*)&staged[qr[a]][h * 76 + d4 * 4];
#pragma unroll
      for (int c = 0; c < 6; ++c)
        kv[c] = *(const float4*)&staged[kr[c]][304 + h * 76 + d4 * 4];
#pragma unroll
      for (int a = 0; a < 3; ++a)
#pragma unroll
        for (int c = 0; c < 6; ++c)
          acc[a][c] += qv[a].x * kv[c].x + qv[a].y * kv[c].y +
                       qv[a].z * kv[c].z + qv[a].w * kv[c].w;
    }
#pragma unroll
    for (int a = 0; a < 3; ++a) {
      float p[6];
#pragma unroll
      for (int c = 0; c < 6; ++c)
        p[c] = (j0 + c < length) ? (acc[a][c] / sdk) : -1e9f;
      float mx = p[0];
#pragma unroll
      for (int c = 1; c < 6; ++c) mx = fmaxf(mx, p[c]);
      mx = fmaxf(mx, __shfl_xor(mx, 1));
      mx = fmaxf(mx, __shfl_xor(mx, 2));
      mx = fmaxf(mx, __shfl_xor(mx, 4));
      float rs = 0.f;
#pragma unroll
      for (int c = 0; c < 6; ++c) { p[c] = expf(p[c] - mx); rs += p[c]; }
      rs += __shfl_xor(rs, 1);
      rs += __shfl_xor(rs, 2);
      rs += __shfl_xor(rs, 4);
      if (i0 + a < length) {
#pragma unroll
        for (int c = 0; c < 6; ++c)
          buf4[h][i0 + a][j0 + c] = p[c] / rs;
      }
    }
  }
  __syncthreads();

  // combine heads ((h0+h1)+(h2+h3))*0.25, diag=1 valid rows; invalid -> 0
  for (int e = tid; e < LG * LG; e += 512) {
    int i = e / LG, j = e - (e / LG) * LG;
    float v = 0.f;
    if (i < length)
      v = ((buf4[0][i][j] + buf4[1][i][j]) +
           (buf4[2][i][j] + buf4[3][i][j])) * 0.25f;
    if (i == j) v = (i < length) ? 1.0f : 0.0f;
    buf4[0][i][j] = v;
  }
  __syncthreads();

  // exact 96th-largest: single-wave binary search (rounds 9-16, passed)
  if (tid < 64) {
    unsigned int vb[36];
#pragma unroll
    for (int v = 0; v < 36; ++v) {
      int e = v * 64 + tid;
      vb[v] = __float_as_uint(buf4[0][e / LG][e % LG]);
    }
    unsigned int cur = 0u;
    for (int bit = 30; bit >= 0; --bit) {
      unsigned int cand = cur | (1u << bit);
      int c = 0;
#pragma unroll
      for (int v = 0; v < 36; ++v) c += (vb[v] >= cand) ? 1 : 0;
      c += __shfl_xor(c, 32); c += __shfl_xor(c, 16);
      c += __shfl_xor(c, 8);  c += __shfl_xor(c, 4);
      c += __shfl_xor(c, 2);  c += __shfl_xor(c, 1);
      if (c >= KTOP) cur = cand;
    }
    if (tid == 0) kthL = __uint_as_float(cur);
  }
  __syncthreads();
  const float kth = kthL;

  // coef/denom/x epilogue (rounds 9-16, passed); nneed <= 4 by construction
  int nc = (nneed > 4) ? 4 : nneed;
  if (tid < nc * LG) {
    int r = tid / LG, j = tid - (tid / LG) * LG;
    int i = nlist[r];
    float aij = buf4[0][i][j];
    float v;
    if (j == i) v = aij;
    else {
      float selv = (aij >= kth ? 1.f : 0.f) + (buf4[0][j][i] >= kth ? 1.f : 0.f);
      v = selv * aij;
    }
    coef[r][j] = v;
  }
  __syncthreads();
  if (tid < nc) {
    float sm = 0.f;
    for (int j = 0; j < LG; ++j) sm += coef[tid][j];
    denomc[tid] = sm + 1.f;
  }
  __syncthreads();
  for (int w = tid; w < nc * (DIM / 4); w += 512) {
    int r = w / (DIM / 4), d4 = w - (w / (DIM / 4)) * (DIM / 4);
    float4 acc = {0.f, 0.f, 0.f, 0.f};
    for (int m = 0; m < nf; ++m) {
      int j = flist[m];
      float a = coef[r][j];
      float4 xv = ((const float4*)(X + (size_t)srcs[j] * DIM))[d4];
      acc.x += a * xv.x; acc.y += a * xv.y;
      acc.z += a * xv.z; acc.w += a * xv.w;
    }
    int n = srcs[nlist[r]] - NA;
    ((float4*)(xout + (size_t)n * DIM))[d4] = acc;
  }
  if (tid < nc) {
    int n = srcs[nlist[tid]] - NA;
    mdg[n] = 1;
    dng[n] = denomc[tid];
  }
}

// ---------------------------------------------------------------------------
// K5: gcn GEMM (unchanged from rounds 6-16, passed)
// ---------------------------------------------------------------------------
__global__ __launch_bounds__(256) void gcn_kernel(
    const float* __restrict__ xg, const float* __restrict__ dng,
    const int* __restrict__ mdg, const float* __restrict__ Wg,
    const float* __restrict__ bg, const float* __restrict__ clause,
    float* __restrict__ out) {
  __shared__ __align__(16) float xs[GTM][GKC];
  __shared__ __align__(16) float ws[GTN][GKC];
  int m0 = blockIdx.x * GTM, n0 = blockIdx.y * GTN;
  int tid = threadIdx.x;
  int ty = tid >> 4;
  int tx = tid & 15;
  float acc[2][4];
#pragma unroll
  for (int a = 0; a < 2; ++a)
#pragma unroll
    for (int c = 0; c < 4; ++c) acc[a][c] = 0.f;

  for (int kc = 0; kc < DIM; kc += GKC) {
    __syncthreads();
    for (int i = tid; i < GTM * (GKC / 4); i += 256) {
      int r = i / (GKC / 4), g = i - r * (GKC / 4);
      *(float4*)&xs[r][g * 4] =
          *(const float4*)&xg[(size_t)(m0 + r) * DIM + kc + g * 4];
    }
    for (int i = tid; i < GTN * (GKC / 4); i += 256) {
      int c = i / (GKC / 4), g = i - c * (GKC / 4);
      int col = n0 + c;
      float4 v = {0.f, 0.f, 0.f, 0.f};
      if (col < DIM)
        v = *(const float4*)&Wg[(size_t)col * DIM + kc + g * 4];
      *(float4*)&ws[c][g * 4] = v;
    }
    __syncthreads();
#pragma unroll 5
    for (int kg = 0; kg < GKC / 4; ++kg) {
      float4 xv[2], wv[4];
#pragma unroll
      for (int a = 0; a < 2; ++a) xv[a] = *(const float4*)&xs[ty * 2 + a][kg * 4];
#pragma unroll
      for (int c = 0; c < 4; ++c) wv[c] = *(const float4*)&ws[tx + 16 * c][kg * 4];
#pragma unroll
      for (int a = 0; a < 2; ++a)
#pragma unroll
        for (int c = 0; c < 4; ++c)
          acc[a][c] += wv[c].x * xv[a].x + wv[c].y * xv[a].y +
                       wv[c].z * xv[a].z + wv[c].w * xv[a].w;
    }
  }

  int md[2]; float dn[2];
#pragma unroll
  for (int a = 0; a < 2; ++a) {
    int row = m0 + ty * 2 + a;
    md[a] = mdg[row];
    dn[a] = dng[row];
  }
#pragma unroll
  for (int cc = 0; cc < 4; ++cc) {
    int col = n0 + tx + 16 * cc;
    if (col < DIM) {
      float bgc = bg[col];
#pragma unroll
      for (int a = 0; a < 2; ++a) {
        int row = m0 + ty * 2 + a;
        float v;
        if (md[a]) v = fmaxf((acc[a][cc] + bgc) / dn[a], 0.f);
        else v = clause[(size_t)row * DIM + col];
        out[(size_t)row * DIM + col] = v;
      }
    }
  }
}

// ---------------------------------------------------------------------------
extern "C" void kernel_launch(void* const* d_in, const int* in_sizes, int n_in,
                              void* d_out, int out_size, void* d_ws, size_t ws_size,
                              hipStream_t stream) {
  (void)in_sizes; (void)n_in; (void)out_size; (void)ws_size;
  const float* input_embed = (const float*)d_in[0];
  const float* clause      = (const float*)d_in[1];
  const float* aa_mask     = (const float*)d_in[2];
  const int*   aa_len      = (const int*)d_in[3];
  const int*   map_AA      = (const int*)d_in[4];
  const int*   map_AA_idx  = (const int*)d_in[5];
  const int*   map_AS      = (const int*)d_in[6];
  const int*   map_AS_idx  = (const int*)d_in[7];
  const float* Wq = (const float*)d_in[8];
  const float* bq = (const float*)d_in[9];
  const float* Wk = (const float*)d_in[10];
  const float* bk = (const float*)d_in[11];
  const float* Wg = (const float*)d_in[12];
  const float* bg = (const float*)d_in[13];
  float* out = (float*)d_out;

  float* X   = (float*)d_ws;                                 // 4096*300 (4.9MB)
  float* QKP = X + (size_t)(NA + NC) * DIM;                  // 3*4096*608 (29.9MB)
  int* slot_src = (int*)(QKP + (size_t)3 * (NA + NC) * QKS); // 512*48
  int* acnt = slot_src + B_SZ * LG;                          // 512
  int* alist = acnt + B_SZ;                                  // 512*16
  float* dng = (float*)alist;                                // 2048 (aliases alist)
  int* mdg = (int*)(dng + NC);                               // 2048 (aliases alist)
  float* xg = (float*)(alist + B_SZ * ACAP);                 // 2048*300 (2.4MB)

  hipMemsetAsync(slot_src, 0xFF, (size_t)B_SZ * LG * sizeof(int), stream);
  hipMemsetAsync(acnt, 0x00, (size_t)B_SZ * sizeof(int), stream);
  build_kernel<<<(NA + 255) / 256, 256, 0, stream>>>(map_AA, map_AA_idx,
                                                     slot_src, acnt, alist);
  clause_kernel<<<NC, 128, 0, stream>>>(clause, map_AS, map_AS_idx, X, slot_src);
  aspect_kernel<<<B_SZ, 256, 0, stream>>>(input_embed, aa_mask, acnt, alist, X);
  dim3 qkgrid((NA + NC) / TM, (2 * DIM + TN - 1) / TN, 3);
  qk_kernel<<<qkgrid, 256, 0, stream>>>(X, Wq, Wk, QKP);
  attn2_kernel<<<B_SZ, 512, 0, stream>>>(QKP, X, bq, bk, slot_src, aa_len,
                                         xg, dng, mdg);
  dim3 ggrid(NC / GTM, (DIM + GTN - 1) / GTN);
  gcn_kernel<<<ggrid, 256, 0, stream>>>(xg, dng, mdg, Wg, bg, clause, out);
}

// Round 18
// 142.226 us; speedup vs baseline: 1.0540x; 1.0540x over previous
//
#include <hip/hip_runtime.h>
#include <math.h>

#define B_SZ 512
#define LG 48
#define T_LEN 128
#define DIM 300
#define NA 2048
#define NC 2048
#define NH 4
#define DK 75
#define KTOP 96
#define ACAP 16
#define TM 64
#define TN 64
#define WSS 156    // ws row stride: 28*tx mod 32 -> 2-way = free
#define QKS 608    // padded QK row: 4 heads x 76 (q) + 4 heads x 76 (k)
#define GTM 32
#define GTN 64
#define GKC 60
#define FCAP2 9    // staged rows: nf <= 8 by construction, +1 bias row
#define SSTR 612   // staged row stride (612 mod 32 = 4 -> spread banks)

// ---------------------------------------------------------------------------
// K0: register aspect slots (atomicMax vs -1 init) + per-sentence aspect lists
// ---------------------------------------------------------------------------
__global__ __launch_bounds__(256) void build_kernel(
    const int* __restrict__ mapAA, const int* __restrict__ mapAAi,
    int* __restrict__ slot_src, int* __restrict__ acnt, int* __restrict__ alist) {
  int n = blockIdx.x * 256 + threadIdx.x;
  if (n >= NA) return;
  int b = mapAA[n];
  atomicMax(&slot_src[b * LG + mapAAi[n]], n);
  int pos = atomicAdd(&acnt[b], 1);
  if (pos < ACAP) alist[b * ACAP + pos] = n;
}

// ---------------------------------------------------------------------------
// K1: grouped aspect embedding v2 — FEATURE-SPLIT. Grid (512, 2): z owns
// float4 cols [0,38) / [38,75). Each output element computed by exactly one
// block with the identical t-ascending fma chain -> bitwise-identical X.
// LDS 27.5KB (was 46.6) -> 5 blocks/CU capacity; grid 1024 -> 4/CU
// (was 2/CU at grid 512) = 2x latency hiding. Half-row embed reads are
// contiguous 608B segments (coalescing preserved).
// ---------------------------------------------------------------------------
__global__ __launch_bounds__(256) void aspect_kernel(
    const float* __restrict__ embed, const float* __restrict__ mask,
    const int* __restrict__ acnt, const int* __restrict__ alist,
    float* __restrict__ X) {
  int b = blockIdx.x;
  int z = blockIdx.y;
  int na = acnt[b]; if (na > ACAP) na = ACAP;
  if (na == 0) return;
  int d0g = z ? 38 : 0;        // global float4 col offset of this half
  int ndh = z ? 37 : 38;       // float4 cols in this half
  __shared__ float mLds[ACAP][T_LEN];
  __shared__ float4 eLds[32][38];
  int tid = threadIdx.x;
  for (int i = tid; i < na * T_LEN; i += 256) {
    int k = i / T_LEN, t = i - k * T_LEN;
    mLds[k][t] = mask[(size_t)alist[b * ACAP + k] * T_LEN + t];
  }
  int nw = na * ndh;
  int i0 = tid, i1 = tid + 256;
  int k0 = i0 / ndh, d0 = i0 - k0 * ndh;
  int k1 = i1 / ndh, d1 = i1 - k1 * ndh;
  float4 a0 = {0, 0, 0, 0}, a1 = {0, 0, 0, 0};
  const float4* e4 = (const float4*)(embed + (size_t)b * T_LEN * DIM);
  for (int t0 = 0; t0 < T_LEN; t0 += 32) {
    __syncthreads();
    for (int i = tid; i < 32 * ndh; i += 256) {
      int t = i / ndh, d = i - t * ndh;
      eLds[t][d] = e4[(size_t)(t0 + t) * DK + d0g + d];
    }
    __syncthreads();
#pragma unroll
    for (int t = 0; t < 32; ++t) {
      if (i0 < nw) {
        float m = mLds[k0][t0 + t]; float4 ev = eLds[t][d0];
        a0.x += m * ev.x; a0.y += m * ev.y; a0.z += m * ev.z; a0.w += m * ev.w;
      }
      if (i1 < nw) {
        float m = mLds[k1][t0 + t]; float4 ev = eLds[t][d1];
        a1.x += m * ev.x; a1.y += m * ev.y; a1.z += m * ev.z; a1.w += m * ev.w;
      }
    }
  }
  if (i0 < nw)
    ((float4*)(X + (size_t)alist[b * ACAP + k0] * DIM))[d0g + d0] = a0;
  if (i1 < nw)
    ((float4*)(X + (size_t)alist[b * ACAP + k1] * DIM))[d0g + d1] = a1;
}

// ---------------------------------------------------------------------------
// K2: clause rows -> X[NA+n]; slot registration (unchanged)
// ---------------------------------------------------------------------------
__global__ __launch_bounds__(128) void clause_kernel(
    const float* __restrict__ clause, const int* __restrict__ mapAS,
    const int* __restrict__ mapASi, float* __restrict__ X,
    int* __restrict__ slot_src) {
  int n = blockIdx.x, t = threadIdx.x;
  const float4* src = (const float4*)(clause + (size_t)n * DIM);
  float4* dst = (float4*)(X + (size_t)(NA + n) * DIM);
  if (t < DIM / 4) dst[t] = src[t];
  if (t == 96) atomicMax(&slot_src[mapAS[n] * LG + mapASi[n]], NA + n);
}

// ---------------------------------------------------------------------------
// K3: QK GEMM v6 — SPLIT-K x2 (round 16 exact, passed twice). Grid (64,10,2):
// z=0 -> k in [0,152), z=1 -> k in [152,300). Bias-free partials, padded-608
// layout; combine (P0+P1)+bias fused into attn2 staging.
// ---------------------------------------------------------------------------
__global__ __launch_bounds__(256) void qk_kernel(
    const float* __restrict__ X, const float* __restrict__ Wq,
    const float* __restrict__ Wk, float* __restrict__ QKP) {
  __shared__ __align__(16) float ws[TN][WSS];
  int z = blockIdx.z;
  int kbase = z ? 152 : 0;
  int ng = z ? 37 : 38;
  int m0 = blockIdx.x * TM, n0 = blockIdx.y * TN;
  int tid = threadIdx.x;
  int ty = tid >> 4;
  int tx = tid & 15;
  float acc[4][4];
#pragma unroll
  for (int a = 0; a < 4; ++a)
#pragma unroll
    for (int c = 0; c < 4; ++c) acc[a][c] = 0.f;

  for (int i = tid; i < TN * ng; i += 256) {
    int c = i / ng, g = i - c * ng;
    int col = n0 + c;
    float4 v = {0.f, 0.f, 0.f, 0.f};
    if (col < 2 * DIM) {
      const float* w = (col < DIM) ? (Wq + (size_t)col * DIM)
                                   : (Wk + (size_t)(col - DIM) * DIM);
      v = *(const float4*)&w[kbase + g * 4];
    }
    *(float4*)&ws[c][g * 4] = v;
  }
  __syncthreads();

  const float* xrow[4];
#pragma unroll
  for (int a = 0; a < 4; ++a)
    xrow[a] = X + (size_t)(m0 + ty * 4 + a) * DIM + kbase;

#pragma unroll 2
  for (int kg = 0; kg < ng; ++kg) {
    float4 xv[4], wv[4];
#pragma unroll
    for (int a = 0; a < 4; ++a) xv[a] = *(const float4*)&xrow[a][kg * 4];
#pragma unroll
    for (int c = 0; c < 4; ++c) wv[c] = *(const float4*)&ws[tx + 16 * c][kg * 4];
#pragma unroll
    for (int a = 0; a < 4; ++a)
#pragma unroll
      for (int c = 0; c < 4; ++c)
        acc[a][c] += wv[c].x * xv[a].x + wv[c].y * xv[a].y +
                     wv[c].z * xv[a].z + wv[c].w * xv[a].w;
  }

  float* out = QKP + (size_t)z * (NA + NC) * QKS;
#pragma unroll
  for (int cc = 0; cc < 4; ++cc) {
    int col = n0 + tx + 16 * cc;
    if (col < 2 * DIM) {
      int off;
      if (col < DIM) off = col + col / DK;
      else { int c2 = col - DIM; off = 304 + c2 + c2 / DK; }
#pragma unroll
      for (int a = 0; a < 4; ++a)
        out[(size_t)(m0 + ty * 4 + a) * QKS + off] = acc[a][cc];
    }
  }
}

// ---------------------------------------------------------------------------
// K4: FUSED attention v3b — round-16 exact code (passed twice; VGPR ~68).
// ---------------------------------------------------------------------------
__global__ __launch_bounds__(512) void attn2_kernel(
    const float* __restrict__ QKP, const float* __restrict__ X,
    const float* __restrict__ bq, const float* __restrict__ bk,
    const int* __restrict__ slot_src, const int* __restrict__ aa_len,
    float* __restrict__ xout, float* __restrict__ dng, int* __restrict__ mdg) {
  int b = blockIdx.x, tid = threadIdx.x;
  __shared__ __align__(16) float staged[FCAP2][SSTR];
  __shared__ float buf4[NH][LG][LG + 1];
  __shared__ float coef[4][LG], denomc[4];
  __shared__ int srcs[LG], nlist[LG], flist[LG], qrow[LG];
  __shared__ float kthL;
  __shared__ int sh_nneed, sh_nf;

  int length = aa_len[b];
  if (length > LG) length = LG;
  if (tid < LG) srcs[tid] = slot_src[b * LG + tid];
  __syncthreads();

  if (tid < 64) {
    bool isneed = (tid < LG) && (srcs[tid] >= NA);
    unsigned long long nm = __ballot(isneed);
    if (isneed) nlist[__popcll(nm & ((1ull << tid) - 1ull))] = tid;
    bool isf = (tid < LG) && (srcs[tid] >= 0);
    unsigned long long fm = __ballot(isf);
    int nf = __popcll(fm);
    if (nf > FCAP2 - 1) nf = FCAP2 - 1;
    if (isf) {
      int c = __popcll(fm & ((1ull << tid) - 1ull));
      if (c < FCAP2 - 1) flist[c] = tid;
    }
    if (tid < LG) {
      int c = __popcll(fm & ((1ull << tid) - 1ull));
      qrow[tid] = (isf && c < FCAP2 - 1) ? c : nf;   // nf = bias row
    }
    if (tid == 0) { sh_nneed = __popcll(nm); sh_nf = nf; }
  }
  __syncthreads();
  int nneed = sh_nneed, nf = sh_nf;

  if (length <= 1) {
    if (tid < nneed) mdg[srcs[nlist[tid]] - NA] = 0;
    return;
  }

  // phase A: bias row
  for (int j = tid; j < 608; j += 512) {
    int half = (j >= 304) ? 1 : 0;
    int jj = j - half * 304;
    int h = jj / 76, d = jj - h * 76;
    float v = 0.f;
    if (d < DK) v = half ? bk[h * DK + d] : bq[h * DK + d];
    staged[nf][j] = v;
  }
  __syncthreads();
  // phase B: filled rows = (P0 + P1) + bias  (split-K combine, fused)
  {
    const float* P0 = QKP;
    const float* P1 = QKP + (size_t)(NA + NC) * QKS;
    for (int i = tid; i < nf * 152; i += 512) {
      int m = i / 152, g = i - m * 152;
      size_t base = (size_t)srcs[flist[m]] * QKS + g * 4;
      float4 a = *(const float4*)&P0[base];
      float4 c = *(const float4*)&P1[base];
      float4 bv = *(const float4*)&staged[nf][g * 4];
      float4 v;
      v.x = (a.x + c.x) + bv.x;
      v.y = (a.y + c.y) + bv.y;
      v.z = (a.z + c.z) + bv.z;
      v.w = (a.w + c.w) + bv.w;
      *(float4*)&staged[m][g * 4] = v;
    }
  }
  __syncthreads();
  if (tid < nf * 8) {   // zero the 8 pad slots per staged row
    int m = tid >> 3, p = tid & 7;
    int pos = (p & 3) * 76 + 75 + ((p >> 2) * 304);
    staged[m][pos] = 0.f;
  }
  __syncthreads();

  const float sdk = sqrtf((float)DK);
  int h = tid >> 7;            // head index 0..3 (128 threads each)
  int t = tid & 127;
  int ti = t >> 3, tj = t & 7;
  int i0 = ti * 3, j0 = tj * 6;

  int qr[3], kr[6];
#pragma unroll
  for (int a = 0; a < 3; ++a) qr[a] = qrow[i0 + a];
#pragma unroll
  for (int c = 0; c < 6; ++c) kr[c] = qrow[j0 + c];

  if (i0 < length) {
    float acc[3][6];
#pragma unroll
    for (int a = 0; a < 3; ++a)
#pragma unroll
      for (int c = 0; c < 6; ++c) acc[a][c] = 0.f;
    for (int d4 = 0; d4 < 19; ++d4) {
      float4 qv[3], kv[6];
#pragma unroll
      for (int a = 0; a < 3; ++a)
        qv[a] = *(const float4*)&staged[qr[a]][h * 76 + d4 * 4];
#pragma unroll
      for (int c = 0; c < 6; ++c)
        kv[c] = *(const float4*)&staged[kr[c]][304 + h * 76 + d4 * 4];
#pragma unroll
      for (int a = 0; a < 3; ++a)
#pragma unroll
        for (int c = 0; c < 6; ++c)
          acc[a][c] += qv[a].x * kv[c].x + qv[a].y * kv[c].y +
                       qv[a].z * kv[c].z + qv[a].w * kv[c].w;
    }
#pragma unroll
    for (int a = 0; a < 3; ++a) {
      float p[6];
#pragma unroll
      for (int c = 0; c < 6; ++c)
        p[c] = (j0 + c < length) ? (acc[a][c] / sdk) : -1e9f;
      float mx = p[0];
#pragma unroll
      for (int c = 1; c < 6; ++c) mx = fmaxf(mx, p[c]);
      mx = fmaxf(mx, __shfl_xor(mx, 1));
      mx = fmaxf(mx, __shfl_xor(mx, 2));
      mx = fmaxf(mx, __shfl_xor(mx, 4));
      float rs = 0.f;
#pragma unroll
      for (int c = 0; c < 6; ++c) { p[c] = expf(p[c] - mx); rs += p[c]; }
      rs += __shfl_xor(rs, 1);
      rs += __shfl_xor(rs, 2);
      rs += __shfl_xor(rs, 4);
      if (i0 + a < length) {
#pragma unroll
        for (int c = 0; c < 6; ++c)
          buf4[h][i0 + a][j0 + c] = p[c] / rs;
      }
    }
  }
  __syncthreads();

  // combine heads ((h0+h1)+(h2+h3))*0.25, diag=1 valid rows; invalid -> 0
  for (int e = tid; e < LG * LG; e += 512) {
    int i = e / LG, j = e - (e / LG) * LG;
    float v = 0.f;
    if (i < length)
      v = ((buf4[0][i][j] + buf4[1][i][j]) +
           (buf4[2][i][j] + buf4[3][i][j])) * 0.25f;
    if (i == j) v = (i < length) ? 1.0f : 0.0f;
    buf4[0][i][j] = v;
  }
  __syncthreads();

  // exact 96th-largest: single-wave binary search (rounds 9-17, passed)
  if (tid < 64) {
    unsigned int vb[36];
#pragma unroll
    for (int v = 0; v < 36; ++v) {
      int e = v * 64 + tid;
      vb[v] = __float_as_uint(buf4[0][e / LG][e % LG]);
    }
    unsigned int cur = 0u;
    for (int bit = 30; bit >= 0; --bit) {
      unsigned int cand = cur | (1u << bit);
      int c = 0;
#pragma unroll
      for (int v = 0; v < 36; ++v) c += (vb[v] >= cand) ? 1 : 0;
      c += __shfl_xor(c, 32); c += __shfl_xor(c, 16);
      c += __shfl_xor(c, 8);  c += __shfl_xor(c, 4);
      c += __shfl_xor(c, 2);  c += __shfl_xor(c, 1);
      if (c >= KTOP) cur = cand;
    }
    if (tid == 0) kthL = __uint_as_float(cur);
  }
  __syncthreads();
  const float kth = kthL;

  // coef/denom/x epilogue (rounds 9-17, passed); nneed <= 4 by construction
  int nc = (nneed > 4) ? 4 : nneed;
  if (tid < nc * LG) {
    int r = tid / LG, j = tid - (tid / LG) * LG;
    int i = nlist[r];
    float aij = buf4[0][i][j];
    float v;
    if (j == i) v = aij;
    else {
      float selv = (aij >= kth ? 1.f : 0.f) + (buf4[0][j][i] >= kth ? 1.f : 0.f);
      v = selv * aij;
    }
    coef[r][j] = v;
  }
  __syncthreads();
  if (tid < nc) {
    float sm = 0.f;
    for (int j = 0; j < LG; ++j) sm += coef[tid][j];
    denomc[tid] = sm + 1.f;
  }
  __syncthreads();
  for (int w = tid; w < nc * (DIM / 4); w += 512) {
    int r = w / (DIM / 4), d4 = w - (w / (DIM / 4)) * (DIM / 4);
    float4 acc = {0.f, 0.f, 0.f, 0.f};
    for (int m = 0; m < nf; ++m) {
      int j = flist[m];
      float a = coef[r][j];
      float4 xv = ((const float4*)(X + (size_t)srcs[j] * DIM))[d4];
      acc.x += a * xv.x; acc.y += a * xv.y;
      acc.z += a * xv.z; acc.w += a * xv.w;
    }
    int n = srcs[nlist[r]] - NA;
    ((float4*)(xout + (size_t)n * DIM))[d4] = acc;
  }
  if (tid < nc) {
    int n = srcs[nlist[tid]] - NA;
    mdg[n] = 1;
    dng[n] = denomc[tid];
  }
}

// ---------------------------------------------------------------------------
// K5: gcn GEMM (unchanged from rounds 6-17, passed)
// ---------------------------------------------------------------------------
__global__ __launch_bounds__(256) void gcn_kernel(
    const float* __restrict__ xg, const float* __restrict__ dng,
    const int* __restrict__ mdg, const float* __restrict__ Wg,
    const float* __restrict__ bg, const float* __restrict__ clause,
    float* __restrict__ out) {
  __shared__ __align__(16) float xs[GTM][GKC];
  __shared__ __align__(16) float ws[GTN][GKC];
  int m0 = blockIdx.x * GTM, n0 = blockIdx.y * GTN;
  int tid = threadIdx.x;
  int ty = tid >> 4;
  int tx = tid & 15;
  float acc[2][4];
#pragma unroll
  for (int a = 0; a < 2; ++a)
#pragma unroll
    for (int c = 0; c < 4; ++c) acc[a][c] = 0.f;

  for (int kc = 0; kc < DIM; kc += GKC) {
    __syncthreads();
    for (int i = tid; i < GTM * (GKC / 4); i += 256) {
      int r = i / (GKC / 4), g = i - r * (GKC / 4);
      *(float4*)&xs[r][g * 4] =
          *(const float4*)&xg[(size_t)(m0 + r) * DIM + kc + g * 4];
    }
    for (int i = tid; i < GTN * (GKC / 4); i += 256) {
      int c = i / (GKC / 4), g = i - c * (GKC / 4);
      int col = n0 + c;
      float4 v = {0.f, 0.f, 0.f, 0.f};
      if (col < DIM)
        v = *(const float4*)&Wg[(size_t)col * DIM + kc + g * 4];
      *(float4*)&ws[c][g * 4] = v;
    }
    __syncthreads();
#pragma unroll 5
    for (int kg = 0; kg < GKC / 4; ++kg) {
      float4 xv[2], wv[4];
#pragma unroll
      for (int a = 0; a < 2; ++a) xv[a] = *(const float4*)&xs[ty * 2 + a][kg * 4];
#pragma unroll
      for (int c = 0; c < 4; ++c) wv[c] = *(const float4*)&ws[tx + 16 * c][kg * 4];
#pragma unroll
      for (int a = 0; a < 2; ++a)
#pragma unroll
        for (int c = 0; c < 4; ++c)
          acc[a][c] += wv[c].x * xv[a].x + wv[c].y * xv[a].y +
                       wv[c].z * xv[a].z + wv[c].w * xv[a].w;
    }
  }

  int md[2]; float dn[2];
#pragma unroll
  for (int a = 0; a < 2; ++a) {
    int row = m0 + ty * 2 + a;
    md[a] = mdg[row];
    dn[a] = dng[row];
  }
#pragma unroll
  for (int cc = 0; cc < 4; ++cc) {
    int col = n0 + tx + 16 * cc;
    if (col < DIM) {
      float bgc = bg[col];
#pragma unroll
      for (int a = 0; a < 2; ++a) {
        int row = m0 + ty * 2 + a;
        float v;
        if (md[a]) v = fmaxf((acc[a][cc] + bgc) / dn[a], 0.f);
        else v = clause[(size_t)row * DIM + col];
        out[(size_t)row * DIM + col] = v;
      }
    }
  }
}

// ---------------------------------------------------------------------------
extern "C" void kernel_launch(void* const* d_in, const int* in_sizes, int n_in,
                              void* d_out, int out_size, void* d_ws, size_t ws_size,
                              hipStream_t stream) {
  (void)in_sizes; (void)n_in; (void)out_size; (void)ws_size;
  const float* input_embed = (const float*)d_in[0];
  const float* clause      = (const float*)d_in[1];
  const float* aa_mask     = (const float*)d_in[2];
  const int*   aa_len      = (const int*)d_in[3];
  const int*   map_AA      = (const int*)d_in[4];
  const int*   map_AA_idx  = (const int*)d_in[5];
  const int*   map_AS      = (const int*)d_in[6];
  const int*   map_AS_idx  = (const int*)d_in[7];
  const float* Wq = (const float*)d_in[8];
  const float* bq = (const float*)d_in[9];
  const float* Wk = (const float*)d_in[10];
  const float* bk = (const float*)d_in[11];
  const float* Wg = (const float*)d_in[12];
  const float* bg = (const float*)d_in[13];
  float* out = (float*)d_out;

  float* X   = (float*)d_ws;                                 // 4096*300 (4.9MB)
  float* QKP = X + (size_t)(NA + NC) * DIM;                  // 2*4096*608 (19.9MB)
  int* slot_src = (int*)(QKP + (size_t)2 * (NA + NC) * QKS); // 512*48
  int* acnt = slot_src + B_SZ * LG;                          // 512
  int* alist = acnt + B_SZ;                                  // 512*16
  float* dng = (float*)alist;                                // 2048 (aliases alist)
  int* mdg = (int*)(dng + NC);                               // 2048 (aliases alist)
  float* xg = (float*)(alist + B_SZ * ACAP);                 // 2048*300 (2.4MB)

  hipMemsetAsync(slot_src, 0xFF, (size_t)B_SZ * LG * sizeof(int), stream);
  hipMemsetAsync(acnt, 0x00, (size_t)B_SZ * sizeof(int), stream);
  build_kernel<<<(NA + 255) / 256, 256, 0, stream>>>(map_AA, map_AA_idx,
                                                     slot_src, acnt, alist);
  clause_kernel<<<NC, 128, 0, stream>>>(clause, map_AS, map_AS_idx, X, slot_src);
  dim3 agrid(B_SZ, 2);
  aspect_kernel<<<agrid, 256, 0, stream>>>(input_embed, aa_mask, acnt, alist, X);
  dim3 qkgrid((NA + NC) / TM, (2 * DIM + TN - 1) / TN, 2);
  qk_kernel<<<qkgrid, 256, 0, stream>>>(X, Wq, Wk, QKP);
  attn2_kernel<<<B_SZ, 512, 0, stream>>>(QKP, X, bq, bk, slot_src, aa_len,
                                         xg, dng, mdg);
  dim3 ggrid(NC / GTM, (DIM + GTN - 1) / GTN);
  gcn_kernel<<<ggrid, 256, 0, stream>>>(xg, dng, mdg, Wg, bg, clause, out);
}

// Round 19
// 136.683 us; speedup vs baseline: 1.0968x; 1.0406x over previous
//
#include <hip/hip_runtime.h>
#include <math.h>

#define B_SZ 512
#define LG 48
#define T_LEN 128
#define DIM 300
#define NA 2048
#define NC 2048
#define NH 4
#define DK 75
#define KTOP 96
#define ACAP 16
#define TM 64
#define TN 64
#define WSS 156    // ws row stride: 28*tx mod 32 -> 2-way = free
#define QKS 608    // padded QK row: 4 heads x 76 (q) + 4 heads x 76 (k)
#define GTM 16
#define GTN 64
#define GKC 60
#define FCAP2 9    // staged rows: nf <= 8 by construction, +1 bias row
#define SSTR 612   // staged row stride (612 mod 32 = 4 -> spread banks)

// ---------------------------------------------------------------------------
// K0: register aspect slots (atomicMax vs -1 init) + per-sentence aspect lists
// ---------------------------------------------------------------------------
__global__ __launch_bounds__(256) void build_kernel(
    const int* __restrict__ mapAA, const int* __restrict__ mapAAi,
    int* __restrict__ slot_src, int* __restrict__ acnt, int* __restrict__ alist) {
  int n = blockIdx.x * 256 + threadIdx.x;
  if (n >= NA) return;
  int b = mapAA[n];
  atomicMax(&slot_src[b * LG + mapAAi[n]], n);
  int pos = atomicAdd(&acnt[b], 1);
  if (pos < ACAP) alist[b * ACAP + pos] = n;
}

// ---------------------------------------------------------------------------
// K1: grouped aspect embedding v3 — FEATURE-SPLIT x4. Grid (512, 4): z owns
// float4 cols [19z, 19z+19) (last: 18). Each output element computed by one
// block with the identical t-ascending fma chain -> bitwise-identical X.
// LDS 17.5KB -> 8 blocks/CU capacity; grid 2048 = 8/CU (was 4/CU at split-2).
// ---------------------------------------------------------------------------
__global__ __launch_bounds__(256) void aspect_kernel(
    const float* __restrict__ embed, const float* __restrict__ mask,
    const int* __restrict__ acnt, const int* __restrict__ alist,
    float* __restrict__ X) {
  int b = blockIdx.x;
  int z = blockIdx.y;
  int na = acnt[b]; if (na > ACAP) na = ACAP;
  if (na == 0) return;
  int d0g = z * 19;            // global float4 col offset of this quarter
  int ndh = (z < 3) ? 19 : 18; // float4 cols in this quarter
  __shared__ float mLds[ACAP][T_LEN];
  __shared__ float4 eLds[32][19];
  int tid = threadIdx.x;
  for (int i = tid; i < na * T_LEN; i += 256) {
    int k = i / T_LEN, t = i - k * T_LEN;
    mLds[k][t] = mask[(size_t)alist[b * ACAP + k] * T_LEN + t];
  }
  int nw = na * ndh;           // <= 16*19 = 304
  int i0 = tid, i1 = tid + 256;
  int k0 = i0 / ndh, d0 = i0 - k0 * ndh;
  int k1 = i1 / ndh, d1 = i1 - k1 * ndh;
  float4 a0 = {0, 0, 0, 0}, a1 = {0, 0, 0, 0};
  const float4* e4 = (const float4*)(embed + (size_t)b * T_LEN * DIM);
  for (int t0 = 0; t0 < T_LEN; t0 += 32) {
    __syncthreads();
    for (int i = tid; i < 32 * ndh; i += 256) {
      int t = i / ndh, d = i - t * ndh;
      eLds[t][d] = e4[(size_t)(t0 + t) * DK + d0g + d];
    }
    __syncthreads();
#pragma unroll
    for (int t = 0; t < 32; ++t) {
      if (i0 < nw) {
        float m = mLds[k0][t0 + t]; float4 ev = eLds[t][d0];
        a0.x += m * ev.x; a0.y += m * ev.y; a0.z += m * ev.z; a0.w += m * ev.w;
      }
      if (i1 < nw) {
        float m = mLds[k1][t0 + t]; float4 ev = eLds[t][d1];
        a1.x += m * ev.x; a1.y += m * ev.y; a1.z += m * ev.z; a1.w += m * ev.w;
      }
    }
  }
  if (i0 < nw)
    ((float4*)(X + (size_t)alist[b * ACAP + k0] * DIM))[d0g + d0] = a0;
  if (i1 < nw)
    ((float4*)(X + (size_t)alist[b * ACAP + k1] * DIM))[d0g + d1] = a1;
}

// ---------------------------------------------------------------------------
// K2: clause rows -> X[NA+n]; slot registration (unchanged)
// ---------------------------------------------------------------------------
__global__ __launch_bounds__(128) void clause_kernel(
    const float* __restrict__ clause, const int* __restrict__ mapAS,
    const int* __restrict__ mapASi, float* __restrict__ X,
    int* __restrict__ slot_src) {
  int n = blockIdx.x, t = threadIdx.x;
  const float4* src = (const float4*)(clause + (size_t)n * DIM);
  float4* dst = (float4*)(X + (size_t)(NA + n) * DIM);
  if (t < DIM / 4) dst[t] = src[t];
  if (t == 96) atomicMax(&slot_src[mapAS[n] * LG + mapASi[n]], NA + n);
}

// ---------------------------------------------------------------------------
// K3: QK GEMM v6 — SPLIT-K x2 (round 16/18 exact, passed 3x)
// ---------------------------------------------------------------------------
__global__ __launch_bounds__(256) void qk_kernel(
    const float* __restrict__ X, const float* __restrict__ Wq,
    const float* __restrict__ Wk, float* __restrict__ QKP) {
  __shared__ __align__(16) float ws[TN][WSS];
  int z = blockIdx.z;
  int kbase = z ? 152 : 0;
  int ng = z ? 37 : 38;
  int m0 = blockIdx.x * TM, n0 = blockIdx.y * TN;
  int tid = threadIdx.x;
  int ty = tid >> 4;
  int tx = tid & 15;
  float acc[4][4];
#pragma unroll
  for (int a = 0; a < 4; ++a)
#pragma unroll
    for (int c = 0; c < 4; ++c) acc[a][c] = 0.f;

  for (int i = tid; i < TN * ng; i += 256) {
    int c = i / ng, g = i - c * ng;
    int col = n0 + c;
    float4 v = {0.f, 0.f, 0.f, 0.f};
    if (col < 2 * DIM) {
      const float* w = (col < DIM) ? (Wq + (size_t)col * DIM)
                                   : (Wk + (size_t)(col - DIM) * DIM);
      v = *(const float4*)&w[kbase + g * 4];
    }
    *(float4*)&ws[c][g * 4] = v;
  }
  __syncthreads();

  const float* xrow[4];
#pragma unroll
  for (int a = 0; a < 4; ++a)
    xrow[a] = X + (size_t)(m0 + ty * 4 + a) * DIM + kbase;

#pragma unroll 2
  for (int kg = 0; kg < ng; ++kg) {
    float4 xv[4], wv[4];
#pragma unroll
    for (int a = 0; a < 4; ++a) xv[a] = *(const float4*)&xrow[a][kg * 4];
#pragma unroll
    for (int c = 0; c < 4; ++c) wv[c] = *(const float4*)&ws[tx + 16 * c][kg * 4];
#pragma unroll
    for (int a = 0; a < 4; ++a)
#pragma unroll
      for (int c = 0; c < 4; ++c)
        acc[a][c] += wv[c].x * xv[a].x + wv[c].y * xv[a].y +
                     wv[c].z * xv[a].z + wv[c].w * xv[a].w;
  }

  float* out = QKP + (size_t)z * (NA + NC) * QKS;
#pragma unroll
  for (int cc = 0; cc < 4; ++cc) {
    int col = n0 + tx + 16 * cc;
    if (col < 2 * DIM) {
      int off;
      if (col < DIM) off = col + col / DK;
      else { int c2 = col - DIM; off = 304 + c2 + c2 / DK; }
#pragma unroll
      for (int a = 0; a < 4; ++a)
        out[(size_t)(m0 + ty * 4 + a) * QKS + off] = acc[a][cc];
    }
  }
}

// ---------------------------------------------------------------------------
// K4: FUSED attention v3b — round-16/18 exact code (passed 3x; VGPR ~52)
// ---------------------------------------------------------------------------
__global__ __launch_bounds__(512) void attn2_kernel(
    const float* __restrict__ QKP, const float* __restrict__ X,
    const float* __restrict__ bq, const float* __restrict__ bk,
    const int* __restrict__ slot_src, const int* __restrict__ aa_len,
    float* __restrict__ xout, float* __restrict__ dng, int* __restrict__ mdg) {
  int b = blockIdx.x, tid = threadIdx.x;
  __shared__ __align__(16) float staged[FCAP2][SSTR];
  __shared__ float buf4[NH][LG][LG + 1];
  __shared__ float coef[4][LG], denomc[4];
  __shared__ int srcs[LG], nlist[LG], flist[LG], qrow[LG];
  __shared__ float kthL;
  __shared__ int sh_nneed, sh_nf;

  int length = aa_len[b];
  if (length > LG) length = LG;
  if (tid < LG) srcs[tid] = slot_src[b * LG + tid];
  __syncthreads();

  if (tid < 64) {
    bool isneed = (tid < LG) && (srcs[tid] >= NA);
    unsigned long long nm = __ballot(isneed);
    if (isneed) nlist[__popcll(nm & ((1ull << tid) - 1ull))] = tid;
    bool isf = (tid < LG) && (srcs[tid] >= 0);
    unsigned long long fm = __ballot(isf);
    int nf = __popcll(fm);
    if (nf > FCAP2 - 1) nf = FCAP2 - 1;
    if (isf) {
      int c = __popcll(fm & ((1ull << tid) - 1ull));
      if (c < FCAP2 - 1) flist[c] = tid;
    }
    if (tid < LG) {
      int c = __popcll(fm & ((1ull << tid) - 1ull));
      qrow[tid] = (isf && c < FCAP2 - 1) ? c : nf;   // nf = bias row
    }
    if (tid == 0) { sh_nneed = __popcll(nm); sh_nf = nf; }
  }
  __syncthreads();
  int nneed = sh_nneed, nf = sh_nf;

  if (length <= 1) {
    if (tid < nneed) mdg[srcs[nlist[tid]] - NA] = 0;
    return;
  }

  // phase A: bias row
  for (int j = tid; j < 608; j += 512) {
    int half = (j >= 304) ? 1 : 0;
    int jj = j - half * 304;
    int h = jj / 76, d = jj - h * 76;
    float v = 0.f;
    if (d < DK) v = half ? bk[h * DK + d] : bq[h * DK + d];
    staged[nf][j] = v;
  }
  __syncthreads();
  // phase B: filled rows = (P0 + P1) + bias  (split-K combine, fused)
  {
    const float* P0 = QKP;
    const float* P1 = QKP + (size_t)(NA + NC) * QKS;
    for (int i = tid; i < nf * 152; i += 512) {
      int m = i / 152, g = i - m * 152;
      size_t base = (size_t)srcs[flist[m]] * QKS + g * 4;
      float4 a = *(const float4*)&P0[base];
      float4 c = *(const float4*)&P1[base];
      float4 bv = *(const float4*)&staged[nf][g * 4];
      float4 v;
      v.x = (a.x + c.x) + bv.x;
      v.y = (a.y + c.y) + bv.y;
      v.z = (a.z + c.z) + bv.z;
      v.w = (a.w + c.w) + bv.w;
      *(float4*)&staged[m][g * 4] = v;
    }
  }
  __syncthreads();
  if (tid < nf * 8) {   // zero the 8 pad slots per staged row
    int m = tid >> 3, p = tid & 7;
    int pos = (p & 3) * 76 + 75 + ((p >> 2) * 304);
    staged[m][pos] = 0.f;
  }
  __syncthreads();

  const float sdk = sqrtf((float)DK);
  int h = tid >> 7;            // head index 0..3 (128 threads each)
  int t = tid & 127;
  int ti = t >> 3, tj = t & 7;
  int i0 = ti * 3, j0 = tj * 6;

  int qr[3], kr[6];
#pragma unroll
  for (int a = 0; a < 3; ++a) qr[a] = qrow[i0 + a];
#pragma unroll
  for (int c = 0; c < 6; ++c) kr[c] = qrow[j0 + c];

  if (i0 < length) {
    float acc[3][6];
#pragma unroll
    for (int a = 0; a < 3; ++a)
#pragma unroll
      for (int c = 0; c < 6; ++c) acc[a][c] = 0.f;
    for (int d4 = 0; d4 < 19; ++d4) {
      float4 qv[3], kv[6];
#pragma unroll
      for (int a = 0; a < 3; ++a)
        qv[a] = *(const float4*)&staged[qr[a]][h * 76 + d4 * 4];
#pragma unroll
      for (int c = 0; c < 6; ++c)
        kv[c] = *(const float4*)&staged[kr[c]][304 + h * 76 + d4 * 4];
#pragma unroll
      for (int a = 0; a < 3; ++a)
#pragma unroll
        for (int c = 0; c < 6; ++c)
          acc[a][c] += qv[a].x * kv[c].x + qv[a].y * kv[c].y +
                       qv[a].z * kv[c].z + qv[a].w * kv[c].w;
    }
#pragma unroll
    for (int a = 0; a < 3; ++a) {
      float p[6];
#pragma unroll
      for (int c = 0; c < 6; ++c)
        p[c] = (j0 + c < length) ? (acc[a][c] / sdk) : -1e9f;
      float mx = p[0];
#pragma unroll
      for (int c = 1; c < 6; ++c) mx = fmaxf(mx, p[c]);
      mx = fmaxf(mx, __shfl_xor(mx, 1));
      mx = fmaxf(mx, __shfl_xor(mx, 2));
      mx = fmaxf(mx, __shfl_xor(mx, 4));
      float rs = 0.f;
#pragma unroll
      for (int c = 0; c < 6; ++c) { p[c] = expf(p[c] - mx); rs += p[c]; }
      rs += __shfl_xor(rs, 1);
      rs += __shfl_xor(rs, 2);
      rs += __shfl_xor(rs, 4);
      if (i0 + a < length) {
#pragma unroll
        for (int c = 0; c < 6; ++c)
          buf4[h][i0 + a][j0 + c] = p[c] / rs;
      }
    }
  }
  __syncthreads();

  // combine heads ((h0+h1)+(h2+h3))*0.25, diag=1 valid rows; invalid -> 0
  for (int e = tid; e < LG * LG; e += 512) {
    int i = e / LG, j = e - (e / LG) * LG;
    float v = 0.f;
    if (i < length)
      v = ((buf4[0][i][j] + buf4[1][i][j]) +
           (buf4[2][i][j] + buf4[3][i][j])) * 0.25f;
    if (i == j) v = (i < length) ? 1.0f : 0.0f;
    buf4[0][i][j] = v;
  }
  __syncthreads();

  // exact 96th-largest: single-wave binary search (rounds 9-18, passed)
  if (tid < 64) {
    unsigned int vb[36];
#pragma unroll
    for (int v = 0; v < 36; ++v) {
      int e = v * 64 + tid;
      vb[v] = __float_as_uint(buf4[0][e / LG][e % LG]);
    }
    unsigned int cur = 0u;
    for (int bit = 30; bit >= 0; --bit) {
      unsigned int cand = cur | (1u << bit);
      int c = 0;
#pragma unroll
      for (int v = 0; v < 36; ++v) c += (vb[v] >= cand) ? 1 : 0;
      c += __shfl_xor(c, 32); c += __shfl_xor(c, 16);
      c += __shfl_xor(c, 8);  c += __shfl_xor(c, 4);
      c += __shfl_xor(c, 2);  c += __shfl_xor(c, 1);
      if (c >= KTOP) cur = cand;
    }
    if (tid == 0) kthL = __uint_as_float(cur);
  }
  __syncthreads();
  const float kth = kthL;

  // coef/denom/x epilogue (rounds 9-18, passed); nneed <= 4 by construction
  int nc = (nneed > 4) ? 4 : nneed;
  if (tid < nc * LG) {
    int r = tid / LG, j = tid - (tid / LG) * LG;
    int i = nlist[r];
    float aij = buf4[0][i][j];
    float v;
    if (j == i) v = aij;
    else {
      float selv = (aij >= kth ? 1.f : 0.f) + (buf4[0][j][i] >= kth ? 1.f : 0.f);
      v = selv * aij;
    }
    coef[r][j] = v;
  }
  __syncthreads();
  if (tid < nc) {
    float sm = 0.f;
    for (int j = 0; j < LG; ++j) sm += coef[tid][j];
    denomc[tid] = sm + 1.f;
  }
  __syncthreads();
  for (int w = tid; w < nc * (DIM / 4); w += 512) {
    int r = w / (DIM / 4), d4 = w - (w / (DIM / 4)) * (DIM / 4);
    float4 acc = {0.f, 0.f, 0.f, 0.f};
    for (int m = 0; m < nf; ++m) {
      int j = flist[m];
      float a = coef[r][j];
      float4 xv = ((const float4*)(X + (size_t)srcs[j] * DIM))[d4];
      acc.x += a * xv.x; acc.y += a * xv.y;
      acc.z += a * xv.z; acc.w += a * xv.w;
    }
    int n = srcs[nlist[r]] - NA;
    ((float4*)(xout + (size_t)n * DIM))[d4] = acc;
  }
  if (tid < nc) {
    int n = srcs[nlist[tid]] - NA;
    mdg[n] = 1;
    dng[n] = denomc[tid];
  }
}

// ---------------------------------------------------------------------------
// K5: gcn GEMM v2 — M-SPLIT. GTM 32->16 (micro 1x4), grid (128,5) = 640
// blocks (2.5/CU, was 1.25/CU at 320). LDS 19.2KB. Per-row k-ascending FMA
// chain element-for-element unchanged -> bitwise-identical output.
// ---------------------------------------------------------------------------
__global__ __launch_bounds__(256) void gcn_kernel(
    const float* __restrict__ xg, const float* __restrict__ dng,
    const int* __restrict__ mdg, const float* __restrict__ Wg,
    const float* __restrict__ bg, const float* __restrict__ clause,
    float* __restrict__ out) {
  __shared__ __align__(16) float xs[GTM][GKC];
  __shared__ __align__(16) float ws[GTN][GKC];
  int m0 = blockIdx.x * GTM, n0 = blockIdx.y * GTN;
  int tid = threadIdx.x;
  int ty = tid >> 4;   // 0..15 -> row ty
  int tx = tid & 15;   // 0..15 -> cols tx+16*cc
  float acc[4];
#pragma unroll
  for (int c = 0; c < 4; ++c) acc[c] = 0.f;

  for (int kc = 0; kc < DIM; kc += GKC) {
    __syncthreads();
    for (int i = tid; i < GTM * (GKC / 4); i += 256) {
      int r = i / (GKC / 4), g = i - r * (GKC / 4);
      *(float4*)&xs[r][g * 4] =
          *(const float4*)&xg[(size_t)(m0 + r) * DIM + kc + g * 4];
    }
    for (int i = tid; i < GTN * (GKC / 4); i += 256) {
      int c = i / (GKC / 4), g = i - c * (GKC / 4);
      int col = n0 + c;
      float4 v = {0.f, 0.f, 0.f, 0.f};
      if (col < DIM)
        v = *(const float4*)&Wg[(size_t)col * DIM + kc + g * 4];
      *(float4*)&ws[c][g * 4] = v;
    }
    __syncthreads();
#pragma unroll 5
    for (int kg = 0; kg < GKC / 4; ++kg) {
      float4 xv = *(const float4*)&xs[ty][kg * 4];
      float4 wv[4];
#pragma unroll
      for (int c = 0; c < 4; ++c) wv[c] = *(const float4*)&ws[tx + 16 * c][kg * 4];
#pragma unroll
      for (int c = 0; c < 4; ++c)
        acc[c] += wv[c].x * xv.x + wv[c].y * xv.y +
                  wv[c].z * xv.z + wv[c].w * xv.w;
    }
  }

  int row = m0 + ty;
  int md1 = mdg[row];
  float dn1 = dng[row];
#pragma unroll
  for (int cc = 0; cc < 4; ++cc) {
    int col = n0 + tx + 16 * cc;
    if (col < DIM) {
      float v;
      if (md1) v = fmaxf((acc[cc] + bg[col]) / dn1, 0.f);
      else v = clause[(size_t)row * DIM + col];
      out[(size_t)row * DIM + col] = v;
    }
  }
}

// ---------------------------------------------------------------------------
extern "C" void kernel_launch(void* const* d_in, const int* in_sizes, int n_in,
                              void* d_out, int out_size, void* d_ws, size_t ws_size,
                              hipStream_t stream) {
  (void)in_sizes; (void)n_in; (void)out_size; (void)ws_size;
  const float* input_embed = (const float*)d_in[0];
  const float* clause      = (const float*)d_in[1];
  const float* aa_mask     = (const float*)d_in[2];
  const int*   aa_len      = (const int*)d_in[3];
  const int*   map_AA      = (const int*)d_in[4];
  const int*   map_AA_idx  = (const int*)d_in[5];
  const int*   map_AS      = (const int*)d_in[6];
  const int*   map_AS_idx  = (const int*)d_in[7];
  const float* Wq = (const float*)d_in[8];
  const float* bq = (const float*)d_in[9];
  const float* Wk = (const float*)d_in[10];
  const float* bk = (const float*)d_in[11];
  const float* Wg = (const float*)d_in[12];
  const float* bg = (const float*)d_in[13];
  float* out = (float*)d_out;

  float* X   = (float*)d_ws;                                 // 4096*300 (4.9MB)
  float* QKP = X + (size_t)(NA + NC) * DIM;                  // 2*4096*608 (19.9MB)
  int* slot_src = (int*)(QKP + (size_t)2 * (NA + NC) * QKS); // 512*48
  int* acnt = slot_src + B_SZ * LG;                          // 512
  int* alist = acnt + B_SZ;                                  // 512*16
  float* dng = (float*)alist;                                // 2048 (aliases alist)
  int* mdg = (int*)(dng + NC);                               // 2048 (aliases alist)
  float* xg = (float*)(alist + B_SZ * ACAP);                 // 2048*300 (2.4MB)

  hipMemsetAsync(slot_src, 0xFF, (size_t)B_SZ * LG * sizeof(int), stream);
  hipMemsetAsync(acnt, 0x00, (size_t)B_SZ * sizeof(int), stream);
  build_kernel<<<(NA + 255) / 256, 256, 0, stream>>>(map_AA, map_AA_idx,
                                                     slot_src, acnt, alist);
  clause_kernel<<<NC, 128, 0, stream>>>(clause, map_AS, map_AS_idx, X, slot_src);
  dim3 agrid(B_SZ, 4);
  aspect_kernel<<<agrid, 256, 0, stream>>>(input_embed, aa_mask, acnt, alist, X);
  dim3 qkgrid((NA + NC) / TM, (2 * DIM + TN - 1) / TN, 2);
  qk_kernel<<<qkgrid, 256, 0, stream>>>(X, Wq, Wk, QKP);
  attn2_kernel<<<B_SZ, 512, 0, stream>>>(QKP, X, bq, bk, slot_src, aa_len,
                                         xg, dng, mdg);
  dim3 ggrid(NC / GTM, (DIM + GTN - 1) / GTN);
  gcn_kernel<<<ggrid, 256, 0, stream>>>(xg, dng, mdg, Wg, bg, clause, out);
}